// Round 4
// baseline (329.232 us; speedup 1.0000x reference)
//
#include <hip/hip_runtime.h>

#define NJ  55
#define BLK 256

// dword-aligned vector types: weight rows start at n*220 B (only 4B-aligned).
// gfx9 global_load_dwordx4/x2 need only dword alignment.
typedef float f4 __attribute__((ext_vector_type(4), aligned(4)));
typedef float f2 __attribute__((ext_vector_type(2), aligned(4)));

// Register-lean streaming LBS @ 8 waves/SIMD:
//  - v3 post-mortem: staged (11 wv/CU), async-dbuf (5), fat-stream (16 wv/CU,
//    52 VGPR row buffer) all sit at ~52-56 us = ~72% of read BW. Only lever
//    untested: occupancy. This version halves the live register set so
//    __launch_bounds__(256,8) -> 32 waves/CU (2x v3) fits without spilling.
//  - row is consumed in 8-joint chunks, double-buffered (named bufs = static
//    indexing, no scratch): load chunk c+1, compute chunk c. The register cap
//    prevents the compiler from hoisting the whole row -> memory issue is
//    spread uniformly across the compute, de-convoying per-CU HBM demand.
//  - SE3 (uniform addr) -> s_load into SGPRs; v_fmac_f32 takes the SE3 value
//    as its one SGPR operand, so the blend costs ZERO VGPRs beyond w + acc.
//  - all row loads share one base address; chunk offsets are imm offsets.
__global__ __launch_bounds__(BLK, 8) void lbs_kernel(
    const float* __restrict__ points,
    const float* __restrict__ weights,
    const float* __restrict__ se3,
    float* __restrict__ out,
    int n_verts)
{
    const int n = blockIdx.x * BLK + threadIdx.x;
    if (n >= n_verts) return;

    const float* __restrict__ wrow = weights + (size_t)n * NJ;
    const float4* __restrict__ M = (const float4*)se3;   // uniform -> s_load/K$

    const float px = points[n * 3 + 0];
    const float py = points[n * 3 + 1];
    const float pz = points[n * 3 + 2];

    float a[12];
    #pragma unroll
    for (int e = 0; e < 12; ++e) a[e] = 0.f;

    #define LBS_STEP(J, W)                                                  \
        do {                                                                \
            const float w_ = (W);                                           \
            const float4 r0 = M[(J) * 4 + 0];                               \
            const float4 r1 = M[(J) * 4 + 1];                               \
            const float4 r2 = M[(J) * 4 + 2];   /* row 3 unused */          \
            a[0] += w_*r0.x; a[1] += w_*r0.y; a[2]  += w_*r0.z; a[3]  += w_*r0.w; \
            a[4] += w_*r1.x; a[5] += w_*r1.y; a[6]  += w_*r1.z; a[7]  += w_*r1.w; \
            a[8] += w_*r2.x; a[9] += w_*r2.y; a[10] += w_*r2.z; a[11] += w_*r2.w; \
        } while (0)

    #define CHUNK8(J0, B0, B1)                                              \
        do {                                                                \
            LBS_STEP((J0) + 0, (B0).x); LBS_STEP((J0) + 1, (B0).y);         \
            LBS_STEP((J0) + 2, (B0).z); LBS_STEP((J0) + 3, (B0).w);         \
            LBS_STEP((J0) + 4, (B1).x); LBS_STEP((J0) + 5, (B1).y);         \
            LBS_STEP((J0) + 6, (B1).z); LBS_STEP((J0) + 7, (B1).w);         \
        } while (0)

    // ---- 2-deep software pipeline over 8-joint chunks (55 = 6*8 + 7) ----
    f4 A0 = *(const f4*)(wrow + 0);
    f4 A1 = *(const f4*)(wrow + 4);
    f4 B0, B1;

    B0 = *(const f4*)(wrow + 8);   B1 = *(const f4*)(wrow + 12);
    CHUNK8(0, A0, A1);
    A0 = *(const f4*)(wrow + 16);  A1 = *(const f4*)(wrow + 20);
    CHUNK8(8, B0, B1);
    B0 = *(const f4*)(wrow + 24);  B1 = *(const f4*)(wrow + 28);
    CHUNK8(16, A0, A1);
    A0 = *(const f4*)(wrow + 32);  A1 = *(const f4*)(wrow + 36);
    CHUNK8(24, B0, B1);
    B0 = *(const f4*)(wrow + 40);  B1 = *(const f4*)(wrow + 44);
    CHUNK8(32, A0, A1);

    // tail loads (joints 48..54) issued before the last full chunk's compute
    f4 T0 = *(const f4*)(wrow + 48);
    f2 T1 = *(const f2*)(wrow + 52);
    const float T2 = wrow[54];
    CHUNK8(40, B0, B1);

    LBS_STEP(48, T0.x); LBS_STEP(49, T0.y); LBS_STEP(50, T0.z); LBS_STEP(51, T0.w);
    LBS_STEP(52, T1.x); LBS_STEP(53, T1.y); LBS_STEP(54, T2);

    #undef CHUNK8
    #undef LBS_STEP

    out[n * 3 + 0] = a[0]*px + a[1]*py + a[2] *pz + a[3];
    out[n * 3 + 1] = a[4]*px + a[5]*py + a[6] *pz + a[7];
    out[n * 3 + 2] = a[8]*px + a[9]*py + a[10]*pz + a[11];
}

extern "C" void kernel_launch(void* const* d_in, const int* in_sizes, int n_in,
                              void* d_out, int out_size, void* d_ws, size_t ws_size,
                              hipStream_t stream)
{
    const float* points  = (const float*)d_in[0];
    const float* weights = (const float*)d_in[1];
    const float* se3     = (const float*)d_in[2];
    float* out = (float*)d_out;

    const int n_verts = in_sizes[0] / 3;              // points is (N,3) fp32
    const int grid = (n_verts + BLK - 1) / BLK;       // 1e6/256 -> 3907
    lbs_kernel<<<grid, BLK, 0, stream>>>(points, weights, se3, out, n_verts);
}